// Round 1
// 577.705 us; speedup vs baseline: 1.0155x; 1.0155x over previous
//
#include <hip/hip_runtime.h>
#include <cstdint>
#include <cstddef>

typedef short short8 __attribute__((ext_vector_type(8)));
typedef short s16x4 __attribute__((ext_vector_type(4)));
typedef float f32x4 __attribute__((ext_vector_type(4)));

typedef const __attribute__((address_space(1))) void* gas_ptr;
typedef __attribute__((address_space(3))) void* las_ptr;

__device__ __forceinline__ unsigned short f2bf(float f) {
    unsigned int u = __float_as_uint(f);
    u += 0x7fffu + ((u >> 16) & 1u);          // RNE (finite inputs)
    return (unsigned short)(u >> 16);
}
__device__ __forceinline__ float bf2f(unsigned short s) {
    return __uint_as_float(((unsigned int)s) << 16);
}
__device__ __forceinline__ float sigmoid_f(float z) {
    return __builtin_amdgcn_rcpf(1.0f + __expf(-z));
}
__device__ __forceinline__ void async_copy16(const void* gp, void* lp) {
    __builtin_amdgcn_global_load_lds((gas_ptr)gp, (las_ptr)lp, 16, 0, 0);
}

// ---------------- converters ----------------
// x: [32768,1024] f32 -> bf16, same layout. 8 elems/thread.
__global__ __launch_bounds__(256) void cvt_x_kernel(const float* __restrict__ in,
                                                    unsigned short* __restrict__ out) {
    size_t i = ((size_t)blockIdx.x * 256 + threadIdx.x) * 8;
    float4 v0 = *(const float4*)(in + i);
    float4 v1 = *(const float4*)(in + i + 4);
    short8 o;
    o[0]=(short)f2bf(v0.x); o[1]=(short)f2bf(v0.y); o[2]=(short)f2bf(v0.z); o[3]=(short)f2bf(v0.w);
    o[4]=(short)f2bf(v1.x); o[5]=(short)f2bf(v1.y); o[6]=(short)f2bf(v1.z); o[7]=(short)f2bf(v1.w);
    *(short8*)(out + i) = o;
}

// W: [1024,4096] f32 -> W_T bf16 [4096,1024]. 64x64 LDS tiles.
__global__ __launch_bounds__(256) void cvt_w_kernel(const float* __restrict__ W,
                                                    unsigned short* __restrict__ Wt) {
    __shared__ unsigned short tile[64][65];
    int bk = blockIdx.x >> 6, bn = blockIdx.x & 63;
    int k0 = bk * 64, n0 = bn * 64;
    int t = threadIdx.x;
    int cr = t >> 6;          // 0..3
    int cc = t & 63;          // 0..63
#pragma unroll
    for (int i = 0; i < 16; ++i) {
        int row = i * 4 + cr;
        tile[row][cc] = f2bf(W[(size_t)(k0 + row) * 4096 + n0 + cc]);
    }
    __syncthreads();
#pragma unroll
    for (int i = 0; i < 16; ++i) {
        int nrow = i * 4 + cr;
        Wt[(size_t)(n0 + nrow) * 1024 + k0 + cc] = tile[cc][nrow];
    }
}

// ---------------- GEMM ----------------
// C[m][n] = sum_k A[m][k]*B_T[n][k], m=b*1024+t (M=32768), n=gate*1024+u (N=4096), K=1024.
// Output: gT bf16 blocked [gate][b][T/8][u][8] (8-t chunks per u, u-major within a t-block)
// so the scan's wave loads (lane = consecutive u, 16 B each) are 1 KB contiguous.
// 128x128 tile, BK=64, 4 waves in 2x2, each wave 4x4 frags of 16x16x32 bf16 MFMA.
__global__ __launch_bounds__(256, 2) void gemm_kernel(const unsigned short* __restrict__ A,
                                                      const unsigned short* __restrict__ Bt,
                                                      const float* __restrict__ bias,
                                                      unsigned short* __restrict__ gT) {
    __shared__ __align__(16) unsigned short As[128 * 64];
    __shared__ __align__(16) unsigned short Bs[128 * 64];

    // band swizzle: 8 m-tiles x 32 n-tiles per band, n fastest
    int bid = blockIdx.x;
    int band = bid >> 8;
    int r = bid & 255;
    int mt = band * 8 + (r >> 5);
    int nt = r & 31;
    int m0 = mt * 128, n0 = nt * 128;

    int tidx = threadIdx.x;
    int lane = tidx & 63, wv = tidx >> 6;
    int wm = wv >> 1, wn = wv & 1;
    int l15 = lane & 15, quad = lane >> 4;

    f32x4 acc[4][4] = {};

    for (int k0 = 0; k0 < 1024; k0 += 64) {
        __syncthreads();
#pragma unroll
        for (int i = 0; i < 4; ++i) {
            int ci = (wv * 4 + i) * 64 + lane;      // 0..1023
            int row = ci >> 3, cc = ci & 7;
            int sc = (cc ^ (row & 7)) << 3;         // swizzled k-offset (elements)
            const unsigned short* ga = A + (size_t)(m0 + row) * 1024 + k0 + sc;
            async_copy16(ga, (char*)As + (wv * 4 + i) * 1024);
            const unsigned short* gb = Bt + (size_t)(n0 + row) * 1024 + k0 + sc;
            async_copy16(gb, (char*)Bs + (wv * 4 + i) * 1024);
        }
        __syncthreads();
#pragma unroll
        for (int kt = 0; kt < 2; ++kt) {
            short8 af[4], bf[4];
#pragma unroll
            for (int mt2 = 0; mt2 < 4; ++mt2) {
                int row = wm * 64 + mt2 * 16 + l15;
                int kc = kt * 4 + quad;
                af[mt2] = *(const short8*)((const char*)As + row * 128 + ((kc ^ (row & 7)) << 4));
            }
#pragma unroll
            for (int nt2 = 0; nt2 < 4; ++nt2) {
                int rown = wn * 64 + nt2 * 16 + l15;
                int kc = kt * 4 + quad;
                bf[nt2] = *(const short8*)((const char*)Bs + rown * 128 + ((kc ^ (rown & 7)) << 4));
            }
#pragma unroll
            for (int mt2 = 0; mt2 < 4; ++mt2)
#pragma unroll
                for (int nt2 = 0; nt2 < 4; ++nt2)
                    acc[mt2][nt2] = __builtin_amdgcn_mfma_f32_16x16x32_bf16(
                        af[mt2], bf[nt2], acc[mt2][nt2], 0, 0, 0);
        }
    }

    // epilogue: C/D layout col=lane&15, row=quad*4+reg.
    // rr=0..3 are consecutive t; t mod 8 is {0,4} per quad, so the s16x4 store
    // stays contiguous inside the 8-t inner block of the new gT layout.
#pragma unroll
    for (int mt2 = 0; mt2 < 4; ++mt2) {
        int mbase = m0 + wm * 64 + mt2 * 16 + quad * 4;
        int b_ = mbase >> 10, t_ = mbase & 1023;
#pragma unroll
        for (int nt2 = 0; nt2 < 4; ++nt2) {
            int n = n0 + wn * 64 + nt2 * 16 + l15;
            int gate = n >> 10, u = n & 1023;
            float bv = bias[n];
            s16x4 pk;
            pk[0] = (short)f2bf(acc[mt2][nt2][0] + bv);
            pk[1] = (short)f2bf(acc[mt2][nt2][1] + bv);
            pk[2] = (short)f2bf(acc[mt2][nt2][2] + bv);
            pk[3] = (short)f2bf(acc[mt2][nt2][3] + bv);
            // gT[gate][b_][t_>>3][u][t_&7]
            size_t off = ((((size_t)(gate * 32 + b_) * 128 + (size_t)(t_ >> 3)) << 13)
                          + ((size_t)u << 3) + (size_t)(t_ & 7));
            *(s16x4*)(gT + off) = pk;
        }
    }
}

// ---------------- sequential scan ----------------
// thread = one (b,u). gT bf16 blocked [4][B][T/8][U][8]; h f32 [B,T,U].
// Wave loads are now 1 KB contiguous (lane u-consecutive, 16 B each).
// 4-deep ring (32 timesteps of prefetch) x 4 gates = 16 outstanding loads/wave.
__global__ __launch_bounds__(64) void scan_kernel(const unsigned short* __restrict__ gT,
                                                  const float* __restrict__ c0,
                                                  const float* __restrict__ Vr,
                                                  const float* __restrict__ Vf,
                                                  float* __restrict__ h) {
    int tid = blockIdx.x * 64 + threadIdx.x;    // 0..32767
    int b = tid >> 10, u = tid & 1023;
    const size_t GS = (size_t)32 * 128 * 8192;          // one gate plane (elements)
    const size_t TBS = 8192;                            // one t-block (1024 u * 8 t)
    const unsigned short* p1 = gT + (size_t)b * (128 * 8192) + ((size_t)u << 3);
    const unsigned short* p2 = p1 + GS;
    const unsigned short* p3 = p2 + GS;
    const unsigned short* p4 = p3 + GS;
    float* hb = h + ((size_t)b << 20) + u;
    float c = c0[(b << 10) + u];
    float vf = Vf[u], vr = Vr[u];

    short8 r1[4], r2[4], r3[4], r4[4];
#pragma unroll
    for (int i = 0; i < 4; ++i) {
        r1[i] = *(const short8*)(p1 + (size_t)i * TBS);
        r2[i] = *(const short8*)(p2 + (size_t)i * TBS);
        r3[i] = *(const short8*)(p3 + (size_t)i * TBS);
        r4[i] = *(const short8*)(p4 + (size_t)i * TBS);
    }
    for (int tb = 0; tb < 128; tb += 4) {
#pragma unroll
        for (int s = 0; s < 4; ++s) {
            short8 a1 = r1[s], a2 = r2[s], a3 = r3[s], a4 = r4[s];
            int tpn = tb + 4 + s;                       // prefetch 4 t-blocks ahead
            if (tpn < 128) {
                size_t o = (size_t)tpn * TBS;
                r1[s] = *(const short8*)(p1 + o);
                r2[s] = *(const short8*)(p2 + o);
                r3[s] = *(const short8*)(p3 + o);
                r4[s] = *(const short8*)(p4 + o);
            }
            int t0 = (tb + s) * 8;
#pragma unroll
            for (int i = 0; i < 8; ++i) {
                float x1 = bf2f((unsigned short)a1[i]);
                float x2 = bf2f((unsigned short)a2[i]);
                float x3 = bf2f((unsigned short)a3[i]);
                float x4 = bf2f((unsigned short)a4[i]);
                float f  = sigmoid_f(x1 + vf * c);
                float cn = fmaf(f, c - x2, x2);        // f*c + (1-f)*a2
                float rr = sigmoid_f(x3 + vr * c);     // uses c_{t-1}
                float hv = fmaf(rr, cn - x4, x4);      // r*c_new + (1-r)*a4
                c = cn;
                hb[(size_t)(t0 + i) << 10] = hv;
            }
        }
    }
}

extern "C" void kernel_launch(void* const* d_in, const int* in_sizes, int n_in,
                              void* d_out, int out_size, void* d_ws, size_t ws_size,
                              hipStream_t stream) {
    const float* x  = (const float*)d_in[0];
    // d_in[1] = h0 (unused by reference)
    const float* c0 = (const float*)d_in[2];
    const float* W  = (const float*)d_in[3];
    const float* b  = (const float*)d_in[4];
    const float* Vr = (const float*)d_in[5];
    const float* Vf = (const float*)d_in[6];
    float* h = (float*)d_out;

    char* ws = (char*)d_ws;
    unsigned short* xb = (unsigned short*)ws;                         // 64 MB
    unsigned short* wt = (unsigned short*)(ws + (size_t)67108864);    // 8 MB
    unsigned short* gT = (unsigned short*)(ws + (size_t)75497472);    // 256 MB

    cvt_x_kernel<<<16384, 256, 0, stream>>>(x, xb);
    cvt_w_kernel<<<1024, 256, 0, stream>>>(W, wt);
    gemm_kernel<<<8192, 256, 0, stream>>>(xb, wt, b, gT);
    scan_kernel<<<512, 64, 0, stream>>>(gT, c0, Vr, Vf, h);
}

// Round 2
// 559.123 us; speedup vs baseline: 1.0493x; 1.0332x over previous
//
#include <hip/hip_runtime.h>
#include <cstdint>
#include <cstddef>

typedef short short8 __attribute__((ext_vector_type(8)));
typedef short s16x4 __attribute__((ext_vector_type(4)));
typedef float f32x4 __attribute__((ext_vector_type(4)));

typedef const __attribute__((address_space(1))) void* gas_ptr;
typedef __attribute__((address_space(3))) void* las_ptr;

__device__ __forceinline__ unsigned short f2bf(float f) {
    unsigned int u = __float_as_uint(f);
    u += 0x7fffu + ((u >> 16) & 1u);          // RNE (finite inputs)
    return (unsigned short)(u >> 16);
}
__device__ __forceinline__ float bf2f(unsigned short s) {
    return __uint_as_float(((unsigned int)s) << 16);
}
__device__ __forceinline__ float sigmoid_f(float z) {
    return __builtin_amdgcn_rcpf(1.0f + __expf(-z));
}
__device__ __forceinline__ void async_copy16(const void* gp, void* lp) {
    __builtin_amdgcn_global_load_lds((gas_ptr)gp, (las_ptr)lp, 16, 0, 0);
}

// ---------------- converters ----------------
// x: [32768,1024] f32 -> bf16, same layout. 8 elems/thread.
__global__ __launch_bounds__(256) void cvt_x_kernel(const float* __restrict__ in,
                                                    unsigned short* __restrict__ out) {
    size_t i = ((size_t)blockIdx.x * 256 + threadIdx.x) * 8;
    float4 v0 = *(const float4*)(in + i);
    float4 v1 = *(const float4*)(in + i + 4);
    short8 o;
    o[0]=(short)f2bf(v0.x); o[1]=(short)f2bf(v0.y); o[2]=(short)f2bf(v0.z); o[3]=(short)f2bf(v0.w);
    o[4]=(short)f2bf(v1.x); o[5]=(short)f2bf(v1.y); o[6]=(short)f2bf(v1.z); o[7]=(short)f2bf(v1.w);
    *(short8*)(out + i) = o;
}

// W: [1024,4096] f32 -> W_T bf16 [4096,1024]. 64x64 LDS tiles.
__global__ __launch_bounds__(256) void cvt_w_kernel(const float* __restrict__ W,
                                                    unsigned short* __restrict__ Wt) {
    __shared__ unsigned short tile[64][65];
    int bk = blockIdx.x >> 6, bn = blockIdx.x & 63;
    int k0 = bk * 64, n0 = bn * 64;
    int t = threadIdx.x;
    int cr = t >> 6;          // 0..3
    int cc = t & 63;          // 0..63
#pragma unroll
    for (int i = 0; i < 16; ++i) {
        int row = i * 4 + cr;
        tile[row][cc] = f2bf(W[(size_t)(k0 + row) * 4096 + n0 + cc]);
    }
    __syncthreads();
#pragma unroll
    for (int i = 0; i < 16; ++i) {
        int nrow = i * 4 + cr;
        Wt[(size_t)(n0 + nrow) * 1024 + k0 + cc] = tile[cc][nrow];
    }
}

// ---------------- GEMM ----------------
// C[m][n] = sum_k A[m][k]*B_T[n][k], m=b*1024+t (M=32768), n=gate*1024+u (N=4096), K=1024.
// Output: gT bf16 TIME-MAJOR blocked [T/8][b][gate][u][8].
//   gate stride = 16 KB, b stride = 64 KB, t-block stride = 2 MB: at any instant the
//   lockstep scan reads ONE contiguous 2 MB window sweeping linearly -> uniform HBM
//   channel utilization (the [gate][b][...] layout camped on one channel set: all
//   streams congruent mod 2 MB / 64 MB).
// 128x128 tile, BK=64, 4 waves in 2x2, each wave 4x4 frags of 16x16x32 bf16 MFMA.
__global__ __launch_bounds__(256, 2) void gemm_kernel(const unsigned short* __restrict__ A,
                                                      const unsigned short* __restrict__ Bt,
                                                      const float* __restrict__ bias,
                                                      unsigned short* __restrict__ gT) {
    __shared__ __align__(16) unsigned short As[128 * 64];
    __shared__ __align__(16) unsigned short Bs[128 * 64];

    // band swizzle: 8 m-tiles x 32 n-tiles per band, n fastest
    int bid = blockIdx.x;
    int band = bid >> 8;
    int r = bid & 255;
    int mt = band * 8 + (r >> 5);
    int nt = r & 31;
    int m0 = mt * 128, n0 = nt * 128;

    int tidx = threadIdx.x;
    int lane = tidx & 63, wv = tidx >> 6;
    int wm = wv >> 1, wn = wv & 1;
    int l15 = lane & 15, quad = lane >> 4;

    f32x4 acc[4][4] = {};

    for (int k0 = 0; k0 < 1024; k0 += 64) {
        __syncthreads();
#pragma unroll
        for (int i = 0; i < 4; ++i) {
            int ci = (wv * 4 + i) * 64 + lane;      // 0..1023
            int row = ci >> 3, cc = ci & 7;
            int sc = (cc ^ (row & 7)) << 3;         // swizzled k-offset (elements)
            const unsigned short* ga = A + (size_t)(m0 + row) * 1024 + k0 + sc;
            async_copy16(ga, (char*)As + (wv * 4 + i) * 1024);
            const unsigned short* gb = Bt + (size_t)(n0 + row) * 1024 + k0 + sc;
            async_copy16(gb, (char*)Bs + (wv * 4 + i) * 1024);
        }
        __syncthreads();
#pragma unroll
        for (int kt = 0; kt < 2; ++kt) {
            short8 af[4], bf[4];
#pragma unroll
            for (int mt2 = 0; mt2 < 4; ++mt2) {
                int row = wm * 64 + mt2 * 16 + l15;
                int kc = kt * 4 + quad;
                af[mt2] = *(const short8*)((const char*)As + row * 128 + ((kc ^ (row & 7)) << 4));
            }
#pragma unroll
            for (int nt2 = 0; nt2 < 4; ++nt2) {
                int rown = wn * 64 + nt2 * 16 + l15;
                int kc = kt * 4 + quad;
                bf[nt2] = *(const short8*)((const char*)Bs + rown * 128 + ((kc ^ (rown & 7)) << 4));
            }
#pragma unroll
            for (int mt2 = 0; mt2 < 4; ++mt2)
#pragma unroll
                for (int nt2 = 0; nt2 < 4; ++nt2)
                    acc[mt2][nt2] = __builtin_amdgcn_mfma_f32_16x16x32_bf16(
                        af[mt2], bf[nt2], acc[mt2][nt2], 0, 0, 0);
        }
    }

    // epilogue: C/D layout col=lane&15, row=quad*4+reg.
    // reg 0..3 are consecutive t; t mod 8 is {0,4} per quad, so the s16x4 store
    // stays inside the 8-t inner block (8-byte aligned).
#pragma unroll
    for (int mt2 = 0; mt2 < 4; ++mt2) {
        int mbase = m0 + wm * 64 + mt2 * 16 + quad * 4;
        int b_ = mbase >> 10, t_ = mbase & 1023;
#pragma unroll
        for (int nt2 = 0; nt2 < 4; ++nt2) {
            int n = n0 + wn * 64 + nt2 * 16 + l15;
            int gate = n >> 10, u = n & 1023;
            float bv = bias[n];
            s16x4 pk;
            pk[0] = (short)f2bf(acc[mt2][nt2][0] + bv);
            pk[1] = (short)f2bf(acc[mt2][nt2][1] + bv);
            pk[2] = (short)f2bf(acc[mt2][nt2][2] + bv);
            pk[3] = (short)f2bf(acc[mt2][nt2][3] + bv);
            // gT[t_>>3][b_][gate][u][t_&7]
            size_t off = ((((size_t)(t_ >> 3) * 32 + (size_t)b_) * 4 + (size_t)gate) << 13)
                         + ((size_t)u << 3) + (size_t)(t_ & 7);
            *(s16x4*)(gT + off) = pk;
        }
    }
}

// ---------------- sequential scan ----------------
// thread = one (b,u). gT bf16 time-major [T/8][B][4][U][8]; h f32 [B,T,U].
// Wave loads: 1 KB contiguous; the 4 gate streams sit 16 KB apart, b streams 64 KB
// apart, so the lockstep device-wide footprint is a contiguous 2 MB sweeping window.
// 4-deep ring (32 timesteps of prefetch) x 4 gates = 16 outstanding loads/wave.
__global__ __launch_bounds__(64) void scan_kernel(const unsigned short* __restrict__ gT,
                                                  const float* __restrict__ c0,
                                                  const float* __restrict__ Vr,
                                                  const float* __restrict__ Vf,
                                                  float* __restrict__ h) {
    int tid = blockIdx.x * 64 + threadIdx.x;    // 0..32767
    int b = tid >> 10, u = tid & 1023;
    const size_t TBS = (size_t)32 * 4 * 8192;           // t-block stride = 1M elems (2 MB)
    const unsigned short* p1 = gT + ((size_t)b * 4) * 8192 + ((size_t)u << 3);
    const unsigned short* p2 = p1 + 8192;               // gate stride = 16 KB
    const unsigned short* p3 = p2 + 8192;
    const unsigned short* p4 = p3 + 8192;
    float* hb = h + ((size_t)b << 20) + u;
    float c = c0[(b << 10) + u];
    float vf = Vf[u], vr = Vr[u];

    short8 r1[4], r2[4], r3[4], r4[4];
#pragma unroll
    for (int i = 0; i < 4; ++i) {
        r1[i] = *(const short8*)(p1 + (size_t)i * TBS);
        r2[i] = *(const short8*)(p2 + (size_t)i * TBS);
        r3[i] = *(const short8*)(p3 + (size_t)i * TBS);
        r4[i] = *(const short8*)(p4 + (size_t)i * TBS);
    }
    for (int tb = 0; tb < 128; tb += 4) {
#pragma unroll
        for (int s = 0; s < 4; ++s) {
            short8 a1 = r1[s], a2 = r2[s], a3 = r3[s], a4 = r4[s];
            int tpn = tb + 4 + s;                       // prefetch 4 t-blocks ahead
            if (tpn < 128) {
                size_t o = (size_t)tpn * TBS;
                r1[s] = *(const short8*)(p1 + o);
                r2[s] = *(const short8*)(p2 + o);
                r3[s] = *(const short8*)(p3 + o);
                r4[s] = *(const short8*)(p4 + o);
            }
            int t0 = (tb + s) * 8;
#pragma unroll
            for (int i = 0; i < 8; ++i) {
                float x1 = bf2f((unsigned short)a1[i]);
                float x2 = bf2f((unsigned short)a2[i]);
                float x3 = bf2f((unsigned short)a3[i]);
                float x4 = bf2f((unsigned short)a4[i]);
                float f  = sigmoid_f(x1 + vf * c);
                float cn = fmaf(f, c - x2, x2);        // f*c + (1-f)*a2
                float rr = sigmoid_f(x3 + vr * c);     // uses c_{t-1}
                float hv = fmaf(rr, cn - x4, x4);      // r*c_new + (1-r)*a4
                c = cn;
                hb[(size_t)(t0 + i) << 10] = hv;
            }
        }
    }
}

extern "C" void kernel_launch(void* const* d_in, const int* in_sizes, int n_in,
                              void* d_out, int out_size, void* d_ws, size_t ws_size,
                              hipStream_t stream) {
    const float* x  = (const float*)d_in[0];
    // d_in[1] = h0 (unused by reference)
    const float* c0 = (const float*)d_in[2];
    const float* W  = (const float*)d_in[3];
    const float* b  = (const float*)d_in[4];
    const float* Vr = (const float*)d_in[5];
    const float* Vf = (const float*)d_in[6];
    float* h = (float*)d_out;

    char* ws = (char*)d_ws;
    unsigned short* xb = (unsigned short*)ws;                         // 64 MB
    unsigned short* wt = (unsigned short*)(ws + (size_t)67108864);    // 8 MB
    unsigned short* gT = (unsigned short*)(ws + (size_t)75497472);    // 256 MB

    cvt_x_kernel<<<16384, 256, 0, stream>>>(x, xb);
    cvt_w_kernel<<<1024, 256, 0, stream>>>(W, wt);
    gemm_kernel<<<8192, 256, 0, stream>>>(xb, wt, b, gT);
    scan_kernel<<<512, 64, 0, stream>>>(gT, c0, Vr, Vf, h);
}

// Round 3
// 550.312 us; speedup vs baseline: 1.0661x; 1.0160x over previous
//
#include <hip/hip_runtime.h>
#include <cstdint>
#include <cstddef>

typedef short short8 __attribute__((ext_vector_type(8)));
typedef short s16x4 __attribute__((ext_vector_type(4)));
typedef float f32x4 __attribute__((ext_vector_type(4)));

typedef const __attribute__((address_space(1))) void* gas_ptr;
typedef __attribute__((address_space(3))) void* las_ptr;

__device__ __forceinline__ unsigned short f2bf(float f) {
    unsigned int u = __float_as_uint(f);
    u += 0x7fffu + ((u >> 16) & 1u);          // RNE (finite inputs)
    return (unsigned short)(u >> 16);
}
__device__ __forceinline__ float bf2f(unsigned short s) {
    return __uint_as_float(((unsigned int)s) << 16);
}
__device__ __forceinline__ float sigmoid_f(float z) {
    return __builtin_amdgcn_rcpf(1.0f + __expf(-z));
}
__device__ __forceinline__ void async_copy16(const void* gp, void* lp) {
    __builtin_amdgcn_global_load_lds((gas_ptr)gp, (las_ptr)lp, 16, 0, 0);
}

// ---------------- converters ----------------
// x: [32768,1024] f32 -> bf16, same layout. 8 elems/thread.
__global__ __launch_bounds__(256) void cvt_x_kernel(const float* __restrict__ in,
                                                    unsigned short* __restrict__ out) {
    size_t i = ((size_t)blockIdx.x * 256 + threadIdx.x) * 8;
    float4 v0 = *(const float4*)(in + i);
    float4 v1 = *(const float4*)(in + i + 4);
    short8 o;
    o[0]=(short)f2bf(v0.x); o[1]=(short)f2bf(v0.y); o[2]=(short)f2bf(v0.z); o[3]=(short)f2bf(v0.w);
    o[4]=(short)f2bf(v1.x); o[5]=(short)f2bf(v1.y); o[6]=(short)f2bf(v1.z); o[7]=(short)f2bf(v1.w);
    *(short8*)(out + i) = o;
}

// W: [1024,4096] f32 -> W_T bf16 [4096,1024]. 64x64 LDS tiles.
__global__ __launch_bounds__(256) void cvt_w_kernel(const float* __restrict__ W,
                                                    unsigned short* __restrict__ Wt) {
    __shared__ unsigned short tile[64][65];
    int bk = blockIdx.x >> 6, bn = blockIdx.x & 63;
    int k0 = bk * 64, n0 = bn * 64;
    int t = threadIdx.x;
    int cr = t >> 6;          // 0..3
    int cc = t & 63;          // 0..63
#pragma unroll
    for (int i = 0; i < 16; ++i) {
        int row = i * 4 + cr;
        tile[row][cc] = f2bf(W[(size_t)(k0 + row) * 4096 + n0 + cc]);
    }
    __syncthreads();
#pragma unroll
    for (int i = 0; i < 16; ++i) {
        int nrow = i * 4 + cr;
        Wt[(size_t)(n0 + nrow) * 1024 + k0 + cc] = tile[cc][nrow];
    }
}

// ---------------- GEMM ----------------
// (unchanged from round 2 — 251 us, MfmaUtil 52%)
// Output: gT bf16 TIME-MAJOR blocked [T/8][b][gate][u][8].
__global__ __launch_bounds__(256, 2) void gemm_kernel(const unsigned short* __restrict__ A,
                                                      const unsigned short* __restrict__ Bt,
                                                      const float* __restrict__ bias,
                                                      unsigned short* __restrict__ gT) {
    __shared__ __align__(16) unsigned short As[128 * 64];
    __shared__ __align__(16) unsigned short Bs[128 * 64];

    // band swizzle: 8 m-tiles x 32 n-tiles per band, n fastest
    int bid = blockIdx.x;
    int band = bid >> 8;
    int r = bid & 255;
    int mt = band * 8 + (r >> 5);
    int nt = r & 31;
    int m0 = mt * 128, n0 = nt * 128;

    int tidx = threadIdx.x;
    int lane = tidx & 63, wv = tidx >> 6;
    int wm = wv >> 1, wn = wv & 1;
    int l15 = lane & 15, quad = lane >> 4;

    f32x4 acc[4][4] = {};

    for (int k0 = 0; k0 < 1024; k0 += 64) {
        __syncthreads();
#pragma unroll
        for (int i = 0; i < 4; ++i) {
            int ci = (wv * 4 + i) * 64 + lane;      // 0..1023
            int row = ci >> 3, cc = ci & 7;
            int sc = (cc ^ (row & 7)) << 3;         // swizzled k-offset (elements)
            const unsigned short* ga = A + (size_t)(m0 + row) * 1024 + k0 + sc;
            async_copy16(ga, (char*)As + (wv * 4 + i) * 1024);
            const unsigned short* gb = Bt + (size_t)(n0 + row) * 1024 + k0 + sc;
            async_copy16(gb, (char*)Bs + (wv * 4 + i) * 1024);
        }
        __syncthreads();
#pragma unroll
        for (int kt = 0; kt < 2; ++kt) {
            short8 af[4], bf[4];
#pragma unroll
            for (int mt2 = 0; mt2 < 4; ++mt2) {
                int row = wm * 64 + mt2 * 16 + l15;
                int kc = kt * 4 + quad;
                af[mt2] = *(const short8*)((const char*)As + row * 128 + ((kc ^ (row & 7)) << 4));
            }
#pragma unroll
            for (int nt2 = 0; nt2 < 4; ++nt2) {
                int rown = wn * 64 + nt2 * 16 + l15;
                int kc = kt * 4 + quad;
                bf[nt2] = *(const short8*)((const char*)Bs + rown * 128 + ((kc ^ (rown & 7)) << 4));
            }
#pragma unroll
            for (int mt2 = 0; mt2 < 4; ++mt2)
#pragma unroll
                for (int nt2 = 0; nt2 < 4; ++nt2)
                    acc[mt2][nt2] = __builtin_amdgcn_mfma_f32_16x16x32_bf16(
                        af[mt2], bf[nt2], acc[mt2][nt2], 0, 0, 0);
        }
    }

    // epilogue: C/D layout col=lane&15, row=quad*4+reg.
#pragma unroll
    for (int mt2 = 0; mt2 < 4; ++mt2) {
        int mbase = m0 + wm * 64 + mt2 * 16 + quad * 4;
        int b_ = mbase >> 10, t_ = mbase & 1023;
#pragma unroll
        for (int nt2 = 0; nt2 < 4; ++nt2) {
            int n = n0 + wn * 64 + nt2 * 16 + l15;
            int gate = n >> 10, u = n & 1023;
            float bv = bias[n];
            s16x4 pk;
            pk[0] = (short)f2bf(acc[mt2][nt2][0] + bv);
            pk[1] = (short)f2bf(acc[mt2][nt2][1] + bv);
            pk[2] = (short)f2bf(acc[mt2][nt2][2] + bv);
            pk[3] = (short)f2bf(acc[mt2][nt2][3] + bv);
            // gT[t_>>3][b_][gate][u][t_&7]
            size_t off = ((((size_t)(t_ >> 3) * 32 + (size_t)b_) * 4 + (size_t)gate) << 13)
                         + ((size_t)u << 3) + (size_t)(t_ & 7);
            *(s16x4*)(gT + off) = pk;
        }
    }
}

// ---------------- sequential scan: producer/consumer ----------------
// gT bf16 time-major [T/8][B][4][U][8]; h f32 [B,T,U].
// Block = 128 thr: wave0 = producer (global_load_lds only -> vmcnt counts ONLY
// copies, so counted waits are exact), wave1 = consumer (64 u-lanes for one b).
// 8-slot LDS ring, 4 KB/slot ([gate][u(64)][t(8)] bf16). Steady-state wait
// vmcnt(24) = 6 groups in flight (depth-7 pipeline, never drained); last 6
// iterations drain with vmcnt(0). Slot math: group j+7 is issued into slot
// (j-1)&7 strictly AFTER barrier j; consumer finished that slot before barrier j.
__global__ __launch_bounds__(128) void scan_kernel(const unsigned short* __restrict__ gT,
                                                   const float* __restrict__ c0,
                                                   const float* __restrict__ Vr,
                                                   const float* __restrict__ Vf,
                                                   float* __restrict__ h) {
    __shared__ __align__(16) unsigned short sbuf[8 * 2048];   // 8 slots x 4096 B

    const int NT = 128;                       // t-blocks
    const int D = 8;                          // ring slots
    int blk = blockIdx.x;                     // 0..511
    int b = blk >> 4;
    int u0 = (blk & 15) << 6;
    int tid = threadIdx.x;
    int wv = tid >> 6;
    int lane = tid & 63;

    if (wv == 0) {
        // ---------- producer ----------
        size_t base = ((size_t)b * 4) * 8192 + ((size_t)(u0 + lane) << 3);
        const unsigned short* pg0 = gT + base;            // gate stride 8192 elems
        const unsigned short* pg1 = pg0 + 8192;
        const unsigned short* pg2 = pg1 + 8192;
        const unsigned short* pg3 = pg2 + 8192;
        // prologue: groups 0..6
#pragma unroll
        for (int g = 0; g < D - 1; ++g) {
            char* ld = (char*)sbuf + (g & 7) * 4096;
            size_t o = (size_t)g << 20;                   // t-block stride = 1M elems
            async_copy16(pg0 + o, ld);
            async_copy16(pg1 + o, ld + 1024);
            async_copy16(pg2 + o, ld + 2048);
            async_copy16(pg3 + o, ld + 3072);
        }
        for (int j = 0; j < NT; ++j) {
            if (j < NT - (D - 2)) {
                asm volatile("s_waitcnt vmcnt(24)" ::: "memory");
            } else {
                asm volatile("s_waitcnt vmcnt(0)" ::: "memory");
            }
            __builtin_amdgcn_s_barrier();
            int g = j + D - 1;
            if (g < NT) {
                char* ld = (char*)sbuf + (g & 7) * 4096;
                size_t o = (size_t)g << 20;
                async_copy16(pg0 + o, ld);
                async_copy16(pg1 + o, ld + 1024);
                async_copy16(pg2 + o, ld + 2048);
                async_copy16(pg3 + o, ld + 3072);
            }
        }
    } else {
        // ---------- consumer ----------
        int u = u0 + lane;
        float c = c0[(b << 10) + u];
        float vf = Vf[u], vr = Vr[u];
        float* hb = h + ((size_t)b << 20) + u;
        const unsigned short* ls = sbuf + (size_t)lane * 8;   // my 16 B within a gate plane
        for (int j = 0; j < NT; ++j) {
            __builtin_amdgcn_s_barrier();
            asm volatile("" ::: "memory");                // don't hoist LDS reads above barrier
            int so = (j & 7) * 2048;                      // slot offset in shorts
            short8 a1 = *(const short8*)(ls + so);
            short8 a2 = *(const short8*)(ls + so + 512);
            short8 a3 = *(const short8*)(ls + so + 1024);
            short8 a4 = *(const short8*)(ls + so + 1536);
            int t0 = j * 8;
#pragma unroll
            for (int i = 0; i < 8; ++i) {
                float x1 = bf2f((unsigned short)a1[i]);
                float x2 = bf2f((unsigned short)a2[i]);
                float x3 = bf2f((unsigned short)a3[i]);
                float x4 = bf2f((unsigned short)a4[i]);
                float f  = sigmoid_f(x1 + vf * c);
                float cn = fmaf(f, c - x2, x2);           // f*c + (1-f)*a2
                float rr = sigmoid_f(x3 + vr * c);        // uses c_{t-1}
                float hv = fmaf(rr, cn - x4, x4);         // r*c_new + (1-r)*a4
                c = cn;
                hb[(size_t)(t0 + i) << 10] = hv;
            }
        }
    }
}

extern "C" void kernel_launch(void* const* d_in, const int* in_sizes, int n_in,
                              void* d_out, int out_size, void* d_ws, size_t ws_size,
                              hipStream_t stream) {
    const float* x  = (const float*)d_in[0];
    // d_in[1] = h0 (unused by reference)
    const float* c0 = (const float*)d_in[2];
    const float* W  = (const float*)d_in[3];
    const float* b  = (const float*)d_in[4];
    const float* Vr = (const float*)d_in[5];
    const float* Vf = (const float*)d_in[6];
    float* h = (float*)d_out;

    char* ws = (char*)d_ws;
    unsigned short* xb = (unsigned short*)ws;                         // 64 MB
    unsigned short* wt = (unsigned short*)(ws + (size_t)67108864);    // 8 MB
    unsigned short* gT = (unsigned short*)(ws + (size_t)75497472);    // 256 MB

    cvt_x_kernel<<<16384, 256, 0, stream>>>(x, xb);
    cvt_w_kernel<<<1024, 256, 0, stream>>>(W, wt);
    gemm_kernel<<<8192, 256, 0, stream>>>(xb, wt, b, gT);
    scan_kernel<<<512, 128, 0, stream>>>(gT, c0, Vr, Vf, h);
}